// Round 6
// baseline (196.661 us; speedup 1.0000x reference)
//
#include <hip/hip_runtime.h>

namespace {
constexpr int CC    = 10;                  // cluster gap window C
constexpr int TT    = 500;                 // time steps
constexpr int NN    = 128;                 // neurons per batch row
constexpr int G     = 10;                  // temporal segments per trace
constexpr int LSEG  = TT / G;              // 50 core steps
constexpr int HALO  = CC;                  // 10
constexpr int NSLOT = 10;                  // ws record: 5 cluster maxes + 5 scalars
constexpr int MAXG  = TT / (CC + 1) + 1;   // 46 max global clusters
}

static __device__ __forceinline__ float comp(const float4& v, int k) {
    return k == 0 ? v.x : k == 1 ? v.y : k == 2 ? v.z : v.w;
}

// ---------------- kernel A: per-segment scan, float4 x 4 neurons per lane ----------------
// 1-wave blocks, 1280 of them (5/CU): staggered dispatch pipelines memory vs compute.
// Each lane owns 4 adjacent neuron columns -> 16 B/lane, 1 KB/wave-load, 4x fewer loads.
// launch_bounds(64,2): non-binding 256-VGPR cap (pipeline needs ~215; R5 proved this
// recipe spill-free; WRITE_SIZE >> 13 MB next round would mean the allocator lost again).
__global__ __launch_bounds__(64, 2)
void seg_scan4(const float* __restrict__ vmem, float* __restrict__ ws) {
    const int s  = blockIdx.x;             // segment 0..9
    const int bp = blockIdx.y;             // batch pair 0..127
    const int l  = threadIdx.x;            // 0..63
    const int b  = bp * 2 + (l >> 5);      // batch
    const int n4 = l & 31;                 // 4-neuron group: neurons 4*n4 .. 4*n4+3
    const int a  = s * LSEG;
    const bool firstSeg = (s == 0), lastSeg = (s == G - 1);
    const float4* __restrict__ col4 = (const float4*)vmem + (size_t)b * TT * 32 + n4;

    __shared__ float stg[5][64][4];        // 5 KB: per-thread cluster-slot scratch
    #pragma unroll
    for (int i = 0; i < 5; ++i)
        #pragma unroll
        for (int k = 0; k < 4; ++k) stg[i][l][k] = 0.0f;

    // ---- rolling 4-buffer chunk pipeline; chunk c covers ofs = -10+10c .. -1+10c ----
    float4 b0[10], b1[10], b2[10], b3[10] = {};

    auto load = [&](float4 (&d)[10], int c) {
        if ((firstSeg && c == 0) || (lastSeg && c == 6)) {    // only edges clamp
            #pragma unroll
            for (int j = 0; j < 10; ++j) {
                int t = a + (-HALO + 10 * c + j);
                t = t < 0 ? 0 : (t > TT - 1 ? TT - 1 : t);    // clamp; masked in scan
                d[j] = col4[t * 32];
            }
        } else {                                              // affine row walk
            const float4* __restrict__ p = col4 + (a - HALO + 10 * c) * 32;
            #pragma unroll
            for (int j = 0; j < 10; ++j) d[j] = p[j * 32];
        }
    };

    int   ls[4], lcount[4], hdne[4], tmn[4], hasu[4];
    float ccm[4], rmax[4], hdm[4], vmx[4], m0[4];
    #pragma unroll
    for (int k = 0; k < 4; ++k) {
        ls[k] = -(1 << 20); lcount[k] = 0; hdne[k] = 0; tmn[k] = 0; hasu[k] = 0;
        ccm[k] = -1e30f; rmax[k] = -1e30f; hdm[k] = -1e30f; vmx[k] = -1e30f; m0[k] = -1e30f;
    }

    auto scan = [&](const float4 (&cur)[10], const float4 (&prev)[10], int c) {
        #pragma unroll
        for (int j = 0; j < 10; ++j) {
            const int ofs = -HALO + 10 * c + j;               // compile-time after inline
            const int t   = a + ofs;
            #pragma unroll
            for (int k = 0; k < 4; ++k) {                     // static k: regs stay regs
                float v = comp(cur[j], k);
                if ((ofs < 0 && firstSeg) || (ofs >= LSEG && lastSeg)) v = -1.0f;
                const bool spike = v >= 0.0f;
                if (ofs >= 0 && ofs < LSEG) {                 // core accounting
                    const float rm2 = fmaxf(rmax[k], v);
                    if (spike) {
                        if (t - ls[k] > CC) {                 // halo gives full C history
                            if (lcount[k] > 0) stg[lcount[k] - 1][l][k] = ccm[k];
                            ccm[k] = v; ++lcount[k];
                        } else if (lcount[k] == 0) { hdne[k] = 1; hdm[k] = fmaxf(hdm[k], rm2); }
                        else ccm[k] = fmaxf(ccm[k], rm2);
                        rmax[k] = -1e30f;
                    } else rmax[k] = rm2;
                    if (v > vmx[k]) { vmx[k] = v; tmn[k] = t; }   // strict >: first argmax
                }
                if (spike) ls[k] = t;                         // halo/tail spikes feed ls
                if (ofs >= HALO) {                            // eval u = t-10 in core
                    const float vu = comp(prev[j], k);        // raw v[t-10]
                    if (ls[k] < t - 2 * CC) { hasu[k] = 1; if (vu > m0[k]) m0[k] = vu; }
                }
            }
        }
    };

    // distance-2 register pipeline over 7 chunks; SB pins loads against re-sinking
    #define SB __builtin_amdgcn_sched_barrier(0)
    load(b0, 0); load(b1, 1); SB;
    load(b2, 2); SB; scan(b0, b3, 0); SB;   // prev unused at c=0,1 (ofs<10 compile-time)
    load(b3, 3); SB; scan(b1, b0, 1); SB;
    load(b0, 4); SB; scan(b2, b1, 2); SB;
    load(b1, 5); SB; scan(b3, b2, 3); SB;
    load(b2, 6); SB; scan(b0, b3, 4); SB;
    scan(b1, b0, 5); scan(b2, b1, 6);
    #undef SB

    #pragma unroll
    for (int k = 0; k < 4; ++k)
        if (lcount[k] > 0) stg[lcount[k] - 1][l][k] = ccm[k];   // close final cluster

    // coalesced float4 output: 10 rows of 512 B per (b,s)
    float* __restrict__ wsl = ws + (size_t)(b * G + s) * NSLOT * NN + n4 * 4;
    #pragma unroll
    for (int i = 0; i < 5; ++i) {
        float4 o;
        o.x = stg[i][l][0]; o.y = stg[i][l][1]; o.z = stg[i][l][2]; o.w = stg[i][l][3];
        *(float4*)(wsl + i * NN) = o;
    }
    float4 opk, ohdm, otg, ovm, om0;
    #pragma unroll
    for (int k = 0; k < 4; ++k) {
        const float pk = __int_as_float(lcount[k] | (hdne[k] << 3) | (hasu[k] << 4) |
                                        (tmn[k] << 5));
        if (k == 0) { opk.x = pk; ohdm.x = hdm[0]; otg.x = rmax[0]; ovm.x = vmx[0]; om0.x = m0[0]; }
        if (k == 1) { opk.y = pk; ohdm.y = hdm[1]; otg.y = rmax[1]; ovm.y = vmx[1]; om0.y = m0[1]; }
        if (k == 2) { opk.z = pk; ohdm.z = hdm[2]; otg.z = rmax[2]; ovm.z = vmx[2]; om0.z = m0[2]; }
        if (k == 3) { opk.w = pk; ohdm.w = hdm[3]; otg.w = rmax[3]; ovm.w = vmx[3]; om0.w = m0[3]; }
    }
    *(float4*)(wsl + 5 * NN) = opk;    // packed
    *(float4*)(wsl + 6 * NN) = ohdm;   // head-piece max
    *(float4*)(wsl + 7 * NN) = otg;    // tail gap max (since last core spike)
    *(float4*)(wsl + 8 * NN) = ovm;    // vmax
    *(float4*)(wsl + 9 * NN) = om0;    // m0
}

// ---------------- kernel B: merge segments + loss (1 wave per 64 neurons) ----------------
__global__ __launch_bounds__(64, 2)
void merge_kernel(const float* __restrict__ vmem, const float* __restrict__ ws,
                  const int* __restrict__ labels, float* __restrict__ out) {
    const int bb = blockIdx.x, lane = threadIdx.x;
    const int b = bb >> 1, n = ((bb & 1) << 6) | lane;
    __shared__ float gl[MAXG * 64];        // 11.8 KB compact global cluster list
    __shared__ float wb[512];              // pass-2 column staging (single wave)

    // ---- preload all 100 ws values to registers; SB prevents re-sinking ----
    const float* __restrict__ wsb = ws + (size_t)b * G * NSLOT * NN + n;
    float f[G * NSLOT];
    #pragma unroll
    for (int q = 0; q < G * NSLOT; ++q) f[q] = wsb[(size_t)q * NN];
    __builtin_amdgcn_sched_barrier(0);

    const int label = labels[b * NN + n];

    int g = 0, g_nc = 0, g_hasu = 0, g_tm = 0;
    bool open = false; float cur = -1e30f, ptg = -1e30f;
    float g_vmax = -1e30f, g_m0 = -1e30f;
    #pragma unroll
    for (int s2 = 0; s2 < G; ++s2) {
        const float* d = &f[s2 * NSLOT];
        const int pk = __float_as_int(d[5]);
        const int k = pk & 7, hne = (pk >> 3) & 1;
        g_nc += k; g_hasu |= (pk >> 4) & 1;
        if (d[8] > g_vmax) { g_vmax = d[8]; g_tm = pk >> 5; }
        if (d[9] > g_m0) g_m0 = d[9];
        if (open) {
            if (hne) { cur = fmaxf(cur, fmaxf(ptg, d[6])); ptg = d[7]; }
            if (k > 0 || !hne) { gl[g * 64 + lane] = cur; ++g; open = false; }
        }
        if (k > 0) {
            #pragma unroll
            for (int i = 0; i < 4; ++i)
                if (i < k - 1) { gl[g * 64 + lane] = d[i]; ++g; }
            float last = d[4];                 // select d[k-1]
            if (k == 1) last = d[0];
            else if (k == 2) last = d[1];
            else if (k == 3) last = d[2];
            else if (k == 4) last = d[3];
            cur = last; open = true; ptg = d[7];
        }
    }
    if (open) { gl[g * 64 + lane] = cur; ++g; }        // g == g_nc

    // pass-2 m_rest: wave-cooperative, rare (needs a 21-step spike-free window)
    const bool need2 = (label > g_nc) && g_hasu && (label - g_nc >= 2);
    float mrest = g_vmax;                              // full2 surrogate default
    unsigned long long bal = __ballot(need2);
    const float* colbase = vmem + (size_t)b * TT * NN;
    while (bal) {
        const int fl = __ffsll(bal) - 1;
        bal &= bal - 1;
        const int   nf    = ((bb & 1) << 6) | fl;      // flagged neuron
        const int   tmf   = __shfl(g_tm, fl);
        const float vmaxf = __shfl(g_vmax, fl);
        #pragma unroll
        for (int j = 0; j < 8; ++j) {                  // stage column: 8 loads/lane
            const int t = lane * 8 + j;
            wb[t] = (t < TT) ? colbase[(size_t)t * NN + nf] : -1.0f;
        }
        asm volatile("s_waitcnt lgkmcnt(0)" ::: "memory");  // wave-lockstep LDS
        __builtin_amdgcn_wave_barrier();
        int ls2 = -1000, lh = 0; float lm = -1e30f;
        const int u0 = lane * 8;
        for (int t2 = u0 - 10; t2 < u0 + 18; ++t2) {
            const float v = (t2 >= 0 && t2 < 512) ? wb[t2] : -1.0f;
            if (v >= 0.0f) ls2 = t2;
            const int u = t2 - 10;
            if (u >= u0 && u < u0 + 8 && u < TT) {
                if (ls2 < u - 10 && (u < tmf - CC / 2 || u > tmf + CC / 2)) {
                    lh = 1; const float vu = wb[u]; if (vu > lm) lm = vu;
                }
            }
        }
        #pragma unroll
        for (int off = 32; off > 0; off >>= 1) {       // wave reduce
            lm = fmaxf(lm, __shfl_down(lm, off));
            lh |= __shfl_down(lh, off);
        }
        const float res = __shfl(lh ? lm : vmaxf, 0);
        if (lane == fl) mrest = res;
        __builtin_amdgcn_wave_barrier();
    }

    // branch select
    float contrib = 0.0f;
    if (label > g_nc) {
        if (!g_hasu) contrib = g_vmax;                 // full0 -> vmax
        else {
            const float dE = (float)(label - g_nc);    // >= 1
            contrib = -((g_m0 + (dE - 1.0f) * mrest) / dE);
        }
    } else if (label < g_nc) {
        const int kk = g_nc - label;                   // 1..nc
        float ssum = 0.0f;
        for (int i = 0; i < kk; ++i) {                 // sum kk smallest cluster maxes
            float mn = 1e30f; int mj = 0;
            for (int jj = 0; jj < g_nc; ++jj) {
                const float x = gl[jj * 64 + lane];
                if (x < mn) { mn = x; mj = jj; }
            }
            ssum += mn; gl[mj * 64 + lane] = 1e30f;
        }
        contrib = ssum / (float)kk;
    }

    out[1 + b * NN + n] = (float)g_nc;                 // spike_output

    float w = contrib;                                 // wave reduce -> 1 atomic/block
    #pragma unroll
    for (int off = 32; off > 0; off >>= 1) w += __shfl_down(w, off);
    if (lane == 0) atomicAdd(out, w);
}

extern "C" void kernel_launch(void* const* d_in, const int* in_sizes, int n_in,
                              void* d_out, int out_size, void* d_ws, size_t ws_size,
                              hipStream_t stream) {
    const float* vmem   = (const float*)d_in[0];
    // d_in[1] (vlastmem) and d_in[3] (ratio) are unused by the reference forward.
    const int*   labels = (const int*)d_in[2];
    float*       out    = (float*)d_out;
    float*       ws     = (float*)d_ws;   // 256*10*10*128*4 = 13.1 MB

    const int B = in_sizes[2] / NN;       // 256

    hipMemsetAsync(out, 0, sizeof(float), stream);     // zero the loss accumulator
    hipLaunchKernelGGL(seg_scan4, dim3(G, B / 2), dim3(64), 0, stream, vmem, ws);
    hipLaunchKernelGGL(merge_kernel, dim3(2 * B), dim3(64), 0, stream,
                       vmem, ws, labels, out);
}

// Round 7
// 161.332 us; speedup vs baseline: 1.2190x; 1.2190x over previous
//
#include <hip/hip_runtime.h>

namespace {
constexpr int CC    = 10;                  // cluster gap window C
constexpr int TT    = 500;                 // time steps
constexpr int NN    = 128;                 // neurons per batch row
constexpr int NG    = 4;                   // temporal groups per block
constexpr int LSEG  = TT / NG;             // 125 core steps per group
constexpr int HALO  = CC;                  // 10
constexpr int NCH   = 15;                  // chunks of 10 covering ofs in [-10, 140)
constexpr int MAXK  = 12;                  // max clusters in a 125-step segment
constexpr int MAXG  = TT / (CC + 1) + 1;   // 46 max global clusters
}

// ---------------- single fused kernel: 4 in-block temporal segments + merge + loss --------
// No workspace at all: segment records pass through LDS; one block per batch.
// NOTE (session journal): this is the round-2 kernel, the best measured total (159.5 us).
// Rounds 3-6 established: (a) binding launch_bounds on multi-wave blocks makes the
// allocator clamp+spill (VGPR 48/64/128 + 18-25 MB scratch writes); (b) total dur_us is
// pinned at ~160 by fixed harness overhead (268 MB ws-poison fill + resets) for any
// kernel-sum <= ~100 us (R2: 57us->159.5; R5: 90us->160.8). Do not "optimize" further.
__global__ __launch_bounds__(512, 2)
void fused_kernel(const float* __restrict__ vmem, const int* __restrict__ labels,
                  float* __restrict__ out) {
    const int tid = threadIdx.x;           // 0..511
    const int g   = tid >> 7;              // temporal group 0..3
    const int n   = tid & 127;             // neuron
    const int b   = blockIdx.x;            // batch
    const int a   = g * LSEG;
    const bool firstSeg = (g == 0), lastSeg = (g == NG - 1);
    const float* __restrict__ col = vmem + (size_t)b * TT * NN + n;

    __shared__ float s_cl[NG][MAXK][NN];   // 24.6 KB per-segment cluster maxes
    __shared__ int   s_pk[NG][NN];         // packed: lcount | hdne<<4 | hasu<<5 | tmn<<6
    __shared__ float s_hdm[NG][NN], s_tg[NG][NN], s_vm[NG][NN], s_m0[NG][NN];
    __shared__ float s_gl[MAXG][NN];       // 23.5 KB global cluster list (merge phase)
    __shared__ float wb[2][512];           // per-wave pass-2 column staging
    __shared__ float red[2];

    // ---- rolling 4-buffer chunk pipeline (chunk c covers ofs = -10+10c .. -1+10c) ----
    float b0[10], b1[10], b2[10], b3[10] = {};

    auto load = [&](float (&d)[10], int c) {
        if ((firstSeg && c == 0) || (lastSeg && c >= 13)) {   // only edges need clamping
            #pragma unroll
            for (int j = 0; j < 10; ++j) {
                int t = a - HALO + 10 * c + j;
                t = t < 0 ? 0 : (t > TT - 1 ? TT - 1 : t);    // clamp; masked in scan
                d[j] = col[t * NN];
            }
        } else {                                              // affine: base + imm offsets
            const float* __restrict__ p = col + (a - HALO + 10 * c) * NN;
            #pragma unroll
            for (int j = 0; j < 10; ++j) d[j] = p[j * NN];
        }
    };

    int   ls = -(1 << 20), lcount = 0, hdne = 0, tmn = 0, hasu = 0;
    float ccm = -1e30f, rmax = -1e30f, hdm = -1e30f, vmx = -1e30f, m0 = -1e30f;

    auto scan = [&](const float (&cur)[10], const float (&prev)[10], int c) {
        #pragma unroll
        for (int j = 0; j < 10; ++j) {
            const int ofs = -HALO + 10 * c + j;               // compile-time after inline
            const int t   = a + ofs;
            float v = cur[j];
            if ((ofs < 0 && firstSeg) || (ofs >= LSEG && lastSeg)) v = -1.0f;
            const bool spike = v >= 0.0f;
            if (ofs >= 0 && ofs < LSEG) {                     // core accounting
                const float rm2 = fmaxf(rmax, v);
                if (spike) {
                    if (t - ls > CC) {                        // halo gives full C history
                        if (lcount > 0) s_cl[g][lcount - 1][n] = ccm;
                        ccm = v; ++lcount;
                    } else if (lcount == 0) { hdne = 1; hdm = fmaxf(hdm, rm2); }
                    else ccm = fmaxf(ccm, rm2);
                    rmax = -1e30f;
                } else rmax = rm2;
                if (v > vmx) { vmx = v; tmn = t; }            // strict >: first argmax
            }
            if (spike) ls = t;                                // halo/tail spikes feed ls
            if (ofs >= HALO && ofs < LSEG + HALO) {           // eval u = t-10 in core
                const float vu = prev[j];                     // raw v[t-10]
                if (ls < t - 2 * CC) { hasu = 1; if (vu > m0) m0 = vu; }
            }
        }
    };

    #define SB __builtin_amdgcn_sched_barrier(0)
    load(b0, 0);  load(b1, 1);  SB;
    load(b2, 2);  SB; scan(b0, b3, 0);  SB;   // prev unused at c=0 (ofs<10 compile-time)
    load(b3, 3);  SB; scan(b1, b0, 1);  SB;
    load(b0, 4);  SB; scan(b2, b1, 2);  SB;
    load(b1, 5);  SB; scan(b3, b2, 3);  SB;
    load(b2, 6);  SB; scan(b0, b3, 4);  SB;
    load(b3, 7);  SB; scan(b1, b0, 5);  SB;
    load(b0, 8);  SB; scan(b2, b1, 6);  SB;
    load(b1, 9);  SB; scan(b3, b2, 7);  SB;
    load(b2, 10); SB; scan(b0, b3, 8);  SB;
    load(b3, 11); SB; scan(b1, b0, 9);  SB;
    load(b0, 12); SB; scan(b2, b1, 10); SB;
    load(b1, 13); SB; scan(b3, b2, 11); SB;
    load(b2, 14); SB; scan(b0, b3, 12); SB;
    scan(b1, b0, 13); scan(b2, b1, 14);
    #undef SB

    if (lcount > 0) s_cl[g][lcount - 1][n] = ccm;   // close final cluster

    s_pk[g][n]  = lcount | (hdne << 4) | (hasu << 5) | (tmn << 6);
    s_hdm[g][n] = hdm;     // head-piece max
    s_tg[g][n]  = rmax;    // tail gap max (since last core spike)
    s_vm[g][n]  = vmx;
    s_m0[g][n]  = m0;
    __syncthreads();

    // ---------------- merge + loss: group 0 only (one thread per neuron) ----------------
    if (tid < NN) {
        const int lane = tid & 63, wv = tid >> 6;
        int gi = 0, g_nc = 0, g_hasu = 0, g_tm = 0;
        bool open = false; float cur = -1e30f, ptg = -1e30f;
        float g_vmax = -1e30f, g_m0 = -1e30f;
        #pragma unroll
        for (int s = 0; s < NG; ++s) {
            const int pk = s_pk[s][tid];
            const int k = pk & 15, hne = (pk >> 4) & 1;
            g_nc += k; g_hasu |= (pk >> 5) & 1;
            const float vmS = s_vm[s][tid];
            if (vmS > g_vmax) { g_vmax = vmS; g_tm = pk >> 6; }   // segment order = t order
            const float m0S = s_m0[s][tid];
            if (m0S > g_m0) g_m0 = m0S;
            if (open) {
                if (hne) { cur = fmaxf(cur, fmaxf(ptg, s_hdm[s][tid])); ptg = s_tg[s][tid]; }
                if (k > 0 || !hne) { s_gl[gi][tid] = cur; ++gi; open = false; }
            }
            if (k > 0) {
                for (int i = 0; i < k - 1; ++i) { s_gl[gi][tid] = s_cl[s][i][tid]; ++gi; }
                cur = s_cl[s][k - 1][tid]; open = true; ptg = s_tg[s][tid];
            }
        }
        if (open) { s_gl[gi][tid] = cur; ++gi; }       // gi == g_nc

        const int label = labels[b * NN + tid];

        // pass-2 m_rest: wave-cooperative, rare (needs a 21-step spike-free window)
        const bool need2 = (label > g_nc) && g_hasu && (label - g_nc >= 2);
        float mrest = g_vmax;                          // full2 surrogate default
        unsigned long long bal = __ballot(need2);      // waves 0/1 fully inside tid<128
        const float* colbase = vmem + (size_t)b * TT * NN;
        float* __restrict__ wbp = wb[wv];
        while (bal) {
            const int fl = __ffsll((unsigned long long)bal) - 1;
            bal &= bal - 1;
            const int   nf    = (wv << 6) | fl;        // flagged neuron (wave's n-range)
            const int   tmf   = __shfl(g_tm, fl);
            const float vmaxf = __shfl(g_vmax, fl);
            #pragma unroll
            for (int j = 0; j < 8; ++j) {              // stage column: 8 loads/lane
                const int t = lane * 8 + j;
                wbp[t] = (t < TT) ? colbase[(size_t)t * NN + nf] : -1.0f;
            }
            asm volatile("s_waitcnt lgkmcnt(0)" ::: "memory");  // wave-lockstep LDS
            __builtin_amdgcn_wave_barrier();
            int ls2 = -1000, lh = 0; float lm = -1e30f;
            const int u0 = lane * 8;
            for (int t2 = u0 - 10; t2 < u0 + 18; ++t2) {
                const float v = (t2 >= 0 && t2 < 512) ? wbp[t2] : -1.0f;
                if (v >= 0.0f) ls2 = t2;
                const int u = t2 - 10;
                if (u >= u0 && u < u0 + 8 && u < TT) {
                    if (ls2 < u - 10 && (u < tmf - CC / 2 || u > tmf + CC / 2)) {
                        lh = 1; const float vu = wbp[u]; if (vu > lm) lm = vu;
                    }
                }
            }
            #pragma unroll
            for (int off = 32; off > 0; off >>= 1) {   // wave reduce
                lm = fmaxf(lm, __shfl_down(lm, off));
                lh |= __shfl_down(lh, off);
            }
            const float res = __shfl(lh ? lm : vmaxf, 0);
            if (lane == fl) mrest = res;
            __builtin_amdgcn_wave_barrier();
        }

        // branch select
        float contrib = 0.0f;
        if (label > g_nc) {
            if (!g_hasu) contrib = g_vmax;             // full0 -> vmax
            else {
                const float dE = (float)(label - g_nc);        // >= 1
                contrib = -((g_m0 + (dE - 1.0f) * mrest) / dE);
            }
        } else if (label < g_nc) {
            const int kk = g_nc - label;               // 1..nc
            float ssum = 0.0f;
            for (int i = 0; i < kk; ++i) {             // sum kk smallest cluster maxes
                float mn = 1e30f; int mj = 0;
                for (int jj = 0; jj < g_nc; ++jj) {
                    const float x = s_gl[jj][tid];
                    if (x < mn) { mn = x; mj = jj; }
                }
                ssum += mn; s_gl[mj][tid] = 1e30f;
            }
            contrib = ssum / (float)kk;
        }

        out[1 + b * NN + tid] = (float)g_nc;           // spike_output

        float w = contrib;                             // 2-wave block reduce
        #pragma unroll
        for (int off = 32; off > 0; off >>= 1) w += __shfl_down(w, off);
        if (lane == 0) red[wv] = w;
    }
    __syncthreads();
    if (tid == 0) atomicAdd(out, red[0] + red[1]);     // 1 atomic per batch (256 total)
}

extern "C" void kernel_launch(void* const* d_in, const int* in_sizes, int n_in,
                              void* d_out, int out_size, void* d_ws, size_t ws_size,
                              hipStream_t stream) {
    const float* vmem   = (const float*)d_in[0];
    // d_in[1] (vlastmem) and d_in[3] (ratio) are unused by the reference forward.
    const int*   labels = (const int*)d_in[2];
    float*       out    = (float*)d_out;
    (void)d_ws; (void)ws_size;                         // workspace deliberately untouched

    const int B = in_sizes[2] / NN;                    // 256

    hipMemsetAsync(out, 0, sizeof(float), stream);     // zero the loss accumulator
    hipLaunchKernelGGL(fused_kernel, dim3(B), dim3(512), 0, stream, vmem, labels, out);
}